// Round 22
// baseline (47.923 us; speedup 1.0000x reference)
//
#include <hip/hip_runtime.h>
#include <math.h>

// Problem constants (fixed shapes from reference)
#define BATCH   8
#define HGRID   64
#define WGRID   64
#define DDIM    256
#define NPTS    1024
#define ROWS    65          // HGRID + 1 (NaN pad row 0)
#define COLS    65
#define KWIN    15          // (2*R_WIN+1)*(2*C_WIN+1) = 3*5
#define BN      (BATCH*NPTS)

#define PIDS_PER_BLK 16
#define THREADS      512    // 8 waves; Phase B: 2 pids per wave
#define NREG         9      // staged q rows in registers
#define NLDS         6      // staged q rows in LDS (per wave slab)

typedef __attribute__((ext_vector_type(8))) short bf16x8;
typedef __attribute__((ext_vector_type(4))) float f32x4;

// Direct-to-LDS 16B/lane: dest = wave-uniform base + lane*16.
__device__ __forceinline__ void gload_lds16(const float* src, float* dst) {
    __builtin_amdgcn_global_load_lds(
        (const __attribute__((address_space(1))) unsigned int*)src,
        (__attribute__((address_space(3))) unsigned int*)dst, 16, 0, 0);
}

// ---------------------------------------------------------------------------
// Kernel 1 (prep_wt): W[c][d] -> WT[d][c], fp32 (transpose only — NO split;
// R16 proved the in-kernel conversion VALU must stay as latency cover).
// 32x32 LDS tile transpose, coalesced both sides. Grid (8,8).
// ---------------------------------------------------------------------------
__global__ __launch_bounds__(256) void prep_wt(const float* __restrict__ W,
                                               float* __restrict__ WT) {
    __shared__ float Ls[32][33];
    const int t  = threadIdx.x;
    const int tx = t & 31;
    const int ty = t >> 5;              // 0..7
    const int d0 = blockIdx.x * 32;
    const int c0 = blockIdx.y * 32;
    #pragma unroll
    for (int r = 0; r < 4; ++r) {
        const int row = ty + r * 8;
        Ls[row][tx] = W[(c0 + row) * DDIM + d0 + tx];
    }
    __syncthreads();
    #pragma unroll
    for (int r = 0; r < 4; ++r) {
        const int row = ty + r * 8;     // d-local
        WT[(d0 + row) * DDIM + c0 + tx] = Ls[tx][row];
    }
}

// ---------------------------------------------------------------------------
// Kernel 2 (fused v17) = v16/v10 (33.7us, session best) with ONE change:
// Phase A's B-operand comes from transposed fp32 WT, so the 16 scalar
// strided W loads per kt become 4 coalesced float4 loads. The split-bf16
// CONVERSION VALU is byte-identical (it's the latency cover — R16).
// Phase B, XCD swizzle, hybrid gather engine: verbatim.
// ---------------------------------------------------------------------------
__global__ __launch_bounds__(THREADS, 4) void fused_local_attn(
        const float* __restrict__ q,
        const float* __restrict__ c_t,
        const float* __restrict__ p_t,
        const float* __restrict__ WT,
        float* __restrict__ out) {

    __shared__ __align__(16) float smem[NLDS * DDIM * 8];   // 48 KB
    float (*Pr)[DDIM] = reinterpret_cast<float (*)[DDIM]>(smem);  // 16KB alias

    const int t    = threadIdx.x;
    const int w    = t >> 6;          // wave 0..7
    const int lane = t & 63;
    const int l15  = lane & 15;
    const int g    = lane >> 4;       // k-group 0..3
    const int bid  = blockIdx.x;
    const int wk   = (bid & 7) * 64 + (bid >> 3);   // XCD-aligned work index
    const int pid0 = wk * PIDS_PER_BLK;
    const int dq   = w * 32;          // this wave's 32-col d-slice
    float* qsw = smem + w * (NLDS * DDIM);   // this wave's staging slab

    // ---------------- Phase A: proj into LDS ----------------
    f32x4 acc0 = (f32x4)0.f;
    f32x4 acc1 = (f32x4)0.f;

    const float* ap  = &c_t[(size_t)(pid0 + l15) * DDIM + g * 8];
    const float* wt0 = &WT[(size_t)(dq + l15) * DDIM + g * 8];       // df=0 col
    const float* wt1 = wt0 + (size_t)16 * DDIM;                      // df=1 col

    #pragma unroll 2
    for (int kt = 0; kt < 8; ++kt) {
        const float4 a01 = *reinterpret_cast<const float4*>(ap + kt * 32);
        const float4 a23 = *reinterpret_cast<const float4*>(ap + kt * 32 + 4);
        const float af[8] = {a01.x, a01.y, a01.z, a01.w, a23.x, a23.y, a23.z, a23.w};
        union { bf16x8 v; unsigned u[4]; } AH, AL;
        #pragma unroll
        for (int i = 0; i < 4; ++i) {
            const unsigned u0 = __float_as_uint(af[2 * i]);
            const unsigned u1 = __float_as_uint(af[2 * i + 1]);
            AH.u[i] = __builtin_amdgcn_perm(u1, u0, 0x07060302u);
            const float l0 = af[2 * i]     - __uint_as_float(u0 & 0xFFFF0000u);
            const float l1 = af[2 * i + 1] - __uint_as_float(u1 & 0xFFFF0000u);
            AL.u[i] = __builtin_amdgcn_perm(__float_as_uint(l1), __float_as_uint(l0),
                                            0x07060302u);
        }

        #pragma unroll
        for (int df = 0; df < 2; ++df) {
            const float* wp = (df == 0) ? wt0 : wt1;
            const float4 b01 = *reinterpret_cast<const float4*>(wp + kt * 32);
            const float4 b23 = *reinterpret_cast<const float4*>(wp + kt * 32 + 4);
            const float bf[8] = {b01.x, b01.y, b01.z, b01.w, b23.x, b23.y, b23.z, b23.w};
            union { bf16x8 v; unsigned u[4]; } BH, BL;
            #pragma unroll
            for (int i = 0; i < 4; ++i) {
                const unsigned u0 = __float_as_uint(bf[2 * i]);
                const unsigned u1 = __float_as_uint(bf[2 * i + 1]);
                BH.u[i] = __builtin_amdgcn_perm(u1, u0, 0x07060302u);
                const float l0 = bf[2 * i]     - __uint_as_float(u0 & 0xFFFF0000u);
                const float l1 = bf[2 * i + 1] - __uint_as_float(u1 & 0xFFFF0000u);
                BL.u[i] = __builtin_amdgcn_perm(__float_as_uint(l1), __float_as_uint(l0),
                                                0x07060302u);
            }
            f32x4 a = (df == 0) ? acc0 : acc1;
            a = __builtin_amdgcn_mfma_f32_16x16x32_bf16(AH.v, BH.v, a, 0, 0, 0);
            a = __builtin_amdgcn_mfma_f32_16x16x32_bf16(AH.v, BL.v, a, 0, 0, 0);
            a = __builtin_amdgcn_mfma_f32_16x16x32_bf16(AL.v, BH.v, a, 0, 0, 0);
            if (df == 0) acc0 = a; else acc1 = a;
        }
    }

    // C/D layout: col = lane&15, row = (lane>>4)*4 + reg  [m89-verified]
    #pragma unroll
    for (int r = 0; r < 4; ++r) {
        Pr[g * 4 + r][dq +  0 + l15] = acc0[r];
        Pr[g * 4 + r][dq + 16 + l15] = acc1[r];
    }
    __syncthreads();

    // Snapshot both pr rows, then Pr's LDS is recycled as staging space.
    const float4 prA = *reinterpret_cast<const float4*>(&Pr[w * 2 + 0][lane * 4]);
    const float4 prB = *reinterpret_cast<const float4*>(&Pr[w * 2 + 1][lane * 4]);
    __syncthreads();

    // ---------------- Phase B: attention, 2 pids per wave -----------------
    #pragma unroll 1
    for (int pp = 0; pp < 2; ++pp) {
        const int pl  = w * 2 + pp;            // pid-local 0..15
        const int pid = pid0 + pl;
        const int b   = pid >> 10;             // / NPTS
        const float4 pr = pp ? prB : prA;
        const float2 ppos = *reinterpret_cast<const float2*>(&p_t[pid * 2]);
        const float p0f = ppos.x;
        const float p1f = ppos.y;
        const int p0 = (int)p0f;
        const int p1 = (int)p1f;

        float re[3], ce[5];
        int rowidx[3], colidx[5];
        #pragma unroll
        for (int i = 0; i < 3; ++i) {
            int rr = p0 + i;
            rr = rr > ROWS ? ROWS : rr;
            rr = (rr == ROWS) ? 0 : rr;        // % ROWS
            rowidx[i] = rr;
            const float rf = (float)(rr - 1 > 0 ? rr - 1 : 0);
            const float dr = rf - p0f;         // / R_WIN (=1)
            re[i] = __expf(-2.0f * dr * dr);
        }
        #pragma unroll
        for (int j = 0; j < 5; ++j) {
            int cc = p1 + j - 1;
            cc = cc < 0 ? 0 : (cc > COLS ? COLS : cc);
            cc = (cc == COLS) ? 0 : cc;        // % COLS
            colidx[j] = cc;
            const float cf = (float)(cc - 1 > 0 ? cc - 1 : 0);
            const float dc = (cf - p1f) * 0.5f; // / C_WIN (=2)
            ce[j] = __expf(-2.0f * dc * dc);
        }

        // Fence: previous round's LDS reads must retire before async writes
        // to the same slab can be issued (vmcnt and lgkmcnt are separate).
        asm volatile("s_waitcnt lgkmcnt(0)" ::: "memory");
        __builtin_amdgcn_sched_barrier(0);

        // ---- Issue ALL 15 gathers: rows 0..NREG-1 -> regs, rest -> LDS ----
        float4 qg[NREG];
        unsigned vmask = 0;
        #pragma unroll
        for (int k = 0; k < KWIN; ++k) {
            const int i = k / 5, j = k % 5;
            const int rr = rowidx[i];
            const int cc = colidx[j];
            const bool valid = (rr != 0) && (cc != 0);   // wave-uniform
            const float* src =
                &q[((size_t)((b * HGRID + rr - 1) * WGRID + cc - 1)) * DDIM + lane * 4];
            if (k < NREG) {
                float4 v = make_float4(0.f, 0.f, 0.f, 0.f);
                if (valid) v = *reinterpret_cast<const float4*>(src);
                qg[k] = v;
            } else {
                if (valid) gload_lds16(src, &qsw[(k - NREG) * DDIM]);
            }
            if (valid) vmask |= (1u << k);
        }
        asm volatile("s_waitcnt vmcnt(0)" ::: "memory");   // ONE wait for all 15
        // Pin register rows once (post-drain: no serialization, no remat).
        #pragma unroll
        for (int k = 0; k < NREG; ++k)
            asm volatile("" : "+v"(qg[k].x), "+v"(qg[k].y), "+v"(qg[k].z), "+v"(qg[k].w));

        // ---- Scores ----
        float score[KWIN];
        #pragma unroll
        for (int k = 0; k < NREG; ++k) {
            const float4 v = qg[k];
            score[k] = fmaf(v.x, pr.x, fmaf(v.y, pr.y, fmaf(v.z, pr.z, v.w * pr.w)));
        }
        #pragma unroll
        for (int k = NREG; k < KWIN; ++k) {
            const float4 v =
                *reinterpret_cast<const float4*>(&qsw[(k - NREG) * DDIM + lane * 4]);
            score[k] = fmaf(v.x, pr.x, fmaf(v.y, pr.y, fmaf(v.z, pr.z, v.w * pr.w)));
        }

        // ---- 15 independent butterfly reductions ----
        #pragma unroll
        for (int k = 0; k < KWIN; ++k) {
            float s = score[k];
            #pragma unroll
            for (int off = 32; off; off >>= 1) s += __shfl_xor(s, off, 64);
            score[k] = ((vmask >> k) & 1u) ? s : -INFINITY;
        }

        // ---- Softmax over K=15 (replicated across lanes) ----
        float mx = score[0];
        #pragma unroll
        for (int k = 1; k < KWIN; ++k) mx = fmaxf(mx, score[k]);
        float sum = 0.f;
        #pragma unroll
        for (int k = 0; k < KWIN; ++k) {
            const float e = __expf(score[k] - mx);
            score[k] = e;
            sum += e;
        }
        const float inv = 1.0f / sum;

        // ---- Weighted sum: reg rows + LDS rows ----
        float ox = 0.f, oy = 0.f, oz = 0.f, ow = 0.f;
        #pragma unroll
        for (int k = 0; k < KWIN; ++k) {
            const int i = k / 5, j = k % 5;
            const float wk2 = score[k] * inv * re[i] * ce[j];
            if (k < NREG) {
                ox = fmaf(wk2, qg[k].x, ox);
                oy = fmaf(wk2, qg[k].y, oy);
                oz = fmaf(wk2, qg[k].z, oz);
                ow = fmaf(wk2, qg[k].w, ow);
            } else if ((vmask >> k) & 1u) {   // guard: stale LDS may be NaN
                const float4 v =
                    *reinterpret_cast<const float4*>(&qsw[(k - NREG) * DDIM + lane * 4]);
                ox = fmaf(wk2, v.x, ox);
                oy = fmaf(wk2, v.y, oy);
                oz = fmaf(wk2, v.z, oz);
                ow = fmaf(wk2, v.w, ow);
            }
        }
        *reinterpret_cast<float4*>(&out[(size_t)pid * DDIM + lane * 4]) =
            make_float4(ox, oy, oz, ow);
    }
}

// ---------------------------------------------------------------------------
extern "C" void kernel_launch(void* const* d_in, const int* in_sizes, int n_in,
                              void* d_out, int out_size, void* d_ws, size_t ws_size,
                              hipStream_t stream) {
    const float* q   = (const float*)d_in[0];
    const float* c_t = (const float*)d_in[1];
    const float* p_t = (const float*)d_in[2];
    const float* W_a = (const float*)d_in[3];
    float* out = (float*)d_out;

    float* WT = (float*)d_ws;   // 256 KB fp32 transposed W

    dim3 wgrid(8, 8);
    prep_wt<<<wgrid, 256, 0, stream>>>(W_a, WT);

    fused_local_attn<<<BN / PIDS_PER_BLK, THREADS, 0, stream>>>(
        q, c_t, p_t, WT, out);
}

// Round 23
// 31.661 us; speedup vs baseline: 1.5136x; 1.5136x over previous
//
#include <hip/hip_runtime.h>
#include <math.h>

// Problem constants (fixed shapes from reference)
#define BATCH   8
#define HGRID   64
#define WGRID   64
#define DDIM    256
#define NPTS    1024
#define ROWS    65          // HGRID + 1 (NaN pad row 0)
#define COLS    65
#define KWIN    15          // (2*R_WIN+1)*(2*C_WIN+1) = 3*5
#define BN      (BATCH*NPTS)

#define PIDS_PER_BLK 16
#define THREADS      512    // 8 waves; Phase B: 2 pids per wave
#define PR_PITCH     260

typedef __attribute__((ext_vector_type(8))) short bf16x8;
typedef __attribute__((ext_vector_type(4))) float f32x4;

// ---------------------------------------------------------------------------
// Fused v18 = v16/v10 (33.7us session best) with ONE change: Phase B stages
// ALL 15 q rows in REGISTERS (qg[15] fp32 = 60 VGPR; ~107 peak live < 128
// cap). The LDS staging engine (slab, lgkm fence, gload_lds, 24 ds_reads
// per round) disappears; LDS = Pr[16][260] = 16.6 KB only.
// Pins ONLY after the single vmcnt(0) drain (v7 rule: post-drain pins
// prevent remat without serializing).
// Phase A untouched (R16: conversion VALU = latency cover; R22: its W
// loads are cross-lane coalesced — transposing made them gathers).
// ---------------------------------------------------------------------------
__global__ __launch_bounds__(THREADS, 4) void fused_local_attn(
        const float* __restrict__ q,
        const float* __restrict__ c_t,
        const float* __restrict__ p_t,
        const float* __restrict__ W,
        float* __restrict__ out) {

    __shared__ __align__(16) float Pr[PIDS_PER_BLK][PR_PITCH];   // 16.6 KB

    const int t    = threadIdx.x;
    const int w    = t >> 6;          // wave 0..7
    const int lane = t & 63;
    const int l15  = lane & 15;
    const int g    = lane >> 4;       // k-group 0..3
    const int bid  = blockIdx.x;
    const int wk   = (bid & 7) * 64 + (bid >> 3);   // XCD x <- batch x
    const int pid0 = wk * PIDS_PER_BLK;
    const int dq   = w * 32;          // this wave's 32-col d-slice

    // ---------------- Phase A: proj into LDS (v16 verbatim) ---------------
    f32x4 acc0 = (f32x4)0.f;
    f32x4 acc1 = (f32x4)0.f;

    const float* ap  = &c_t[(size_t)(pid0 + l15) * DDIM + g * 8];
    const float* wp0 = &W[(size_t)(g * 8) * DDIM + dq + l15];        // df=0
    const float* wp1 = wp0 + 16;                                      // df=1

    #pragma unroll 2
    for (int kt = 0; kt < 8; ++kt) {
        const float4 a01 = *reinterpret_cast<const float4*>(ap + kt * 32);
        const float4 a23 = *reinterpret_cast<const float4*>(ap + kt * 32 + 4);
        const float af[8] = {a01.x, a01.y, a01.z, a01.w, a23.x, a23.y, a23.z, a23.w};
        union { bf16x8 v; unsigned u[4]; } AH, AL;
        #pragma unroll
        for (int i = 0; i < 4; ++i) {
            const unsigned u0 = __float_as_uint(af[2 * i]);
            const unsigned u1 = __float_as_uint(af[2 * i + 1]);
            AH.u[i] = __builtin_amdgcn_perm(u1, u0, 0x07060302u);
            const float l0 = af[2 * i]     - __uint_as_float(u0 & 0xFFFF0000u);
            const float l1 = af[2 * i + 1] - __uint_as_float(u1 & 0xFFFF0000u);
            AL.u[i] = __builtin_amdgcn_perm(__float_as_uint(l1), __float_as_uint(l0),
                                            0x07060302u);
        }

        #pragma unroll
        for (int df = 0; df < 2; ++df) {
            const float* wp = (df == 0) ? wp0 : wp1;
            float bf[8];
            #pragma unroll
            for (int i = 0; i < 8; ++i)
                bf[i] = wp[(size_t)(kt * 32 + i) * DDIM];
            union { bf16x8 v; unsigned u[4]; } BH, BL;
            #pragma unroll
            for (int i = 0; i < 4; ++i) {
                const unsigned u0 = __float_as_uint(bf[2 * i]);
                const unsigned u1 = __float_as_uint(bf[2 * i + 1]);
                BH.u[i] = __builtin_amdgcn_perm(u1, u0, 0x07060302u);
                const float l0 = bf[2 * i]     - __uint_as_float(u0 & 0xFFFF0000u);
                const float l1 = bf[2 * i + 1] - __uint_as_float(u1 & 0xFFFF0000u);
                BL.u[i] = __builtin_amdgcn_perm(__float_as_uint(l1), __float_as_uint(l0),
                                                0x07060302u);
            }
            f32x4 a = (df == 0) ? acc0 : acc1;
            a = __builtin_amdgcn_mfma_f32_16x16x32_bf16(AH.v, BH.v, a, 0, 0, 0);
            a = __builtin_amdgcn_mfma_f32_16x16x32_bf16(AH.v, BL.v, a, 0, 0, 0);
            a = __builtin_amdgcn_mfma_f32_16x16x32_bf16(AL.v, BH.v, a, 0, 0, 0);
            if (df == 0) acc0 = a; else acc1 = a;
        }
    }

    // C/D layout: col = lane&15, row = (lane>>4)*4 + reg  [m89-verified]
    #pragma unroll
    for (int r = 0; r < 4; ++r) {
        Pr[g * 4 + r][dq +  0 + l15] = acc0[r];
        Pr[g * 4 + r][dq + 16 + l15] = acc1[r];
    }
    __syncthreads();

    // ---------------- Phase B: attention, 2 pids per wave, pure-reg -------
    #pragma unroll 1
    for (int pp = 0; pp < 2; ++pp) {
        const int pl  = w * 2 + pp;            // pid-local 0..15
        const int pid = pid0 + pl;
        const int b   = pid >> 10;             // / NPTS
        const float4 pr = *reinterpret_cast<const float4*>(&Pr[pl][lane * 4]);
        const float2 ppos = *reinterpret_cast<const float2*>(&p_t[pid * 2]);
        const float p0f = ppos.x;
        const float p1f = ppos.y;
        const int p0 = (int)p0f;
        const int p1 = (int)p1f;

        float re[3], ce[5];
        int rowidx[3], colidx[5];
        #pragma unroll
        for (int i = 0; i < 3; ++i) {
            int rr = p0 + i;
            rr = rr > ROWS ? ROWS : rr;
            rr = (rr == ROWS) ? 0 : rr;        // % ROWS
            rowidx[i] = rr;
            const float rf = (float)(rr - 1 > 0 ? rr - 1 : 0);
            const float dr = rf - p0f;         // / R_WIN (=1)
            re[i] = __expf(-2.0f * dr * dr);
        }
        #pragma unroll
        for (int j = 0; j < 5; ++j) {
            int cc = p1 + j - 1;
            cc = cc < 0 ? 0 : (cc > COLS ? COLS : cc);
            cc = (cc == COLS) ? 0 : cc;        // % COLS
            colidx[j] = cc;
            const float cf = (float)(cc - 1 > 0 ? cc - 1 : 0);
            const float dc = (cf - p1f) * 0.5f; // / C_WIN (=2)
            ce[j] = __expf(-2.0f * dc * dc);
        }

        // ---- Issue ALL 15 gathers into registers ----
        float4 qg[KWIN];
        unsigned vmask = 0;
        #pragma unroll
        for (int k = 0; k < KWIN; ++k) {
            const int i = k / 5, j = k % 5;
            const int rr = rowidx[i];
            const int cc = colidx[j];
            const bool valid = (rr != 0) && (cc != 0);   // wave-uniform
            float4 v = make_float4(0.f, 0.f, 0.f, 0.f);
            if (valid) {
                v = *reinterpret_cast<const float4*>(
                    &q[((size_t)((b * HGRID + rr - 1) * WGRID + cc - 1)) * DDIM
                       + lane * 4]);
                vmask |= (1u << k);
            }
            qg[k] = v;
        }
        asm volatile("s_waitcnt vmcnt(0)" ::: "memory");   // ONE wait for all 15
        // Pin once, post-drain (prevents remat without serializing).
        #pragma unroll
        for (int k = 0; k < KWIN; ++k)
            asm volatile("" : "+v"(qg[k].x), "+v"(qg[k].y), "+v"(qg[k].z), "+v"(qg[k].w));

        // ---- Scores ----
        float score[KWIN];
        #pragma unroll
        for (int k = 0; k < KWIN; ++k) {
            const float4 v = qg[k];
            score[k] = fmaf(v.x, pr.x, fmaf(v.y, pr.y, fmaf(v.z, pr.z, v.w * pr.w)));
        }

        // ---- 15 independent butterfly reductions ----
        #pragma unroll
        for (int k = 0; k < KWIN; ++k) {
            float s = score[k];
            #pragma unroll
            for (int off = 32; off; off >>= 1) s += __shfl_xor(s, off, 64);
            score[k] = ((vmask >> k) & 1u) ? s : -INFINITY;
        }

        // ---- Softmax over K=15 (replicated across lanes) ----
        float mx = score[0];
        #pragma unroll
        for (int k = 1; k < KWIN; ++k) mx = fmaxf(mx, score[k]);
        float sum = 0.f;
        #pragma unroll
        for (int k = 0; k < KWIN; ++k) {
            const float e = __expf(score[k] - mx);
            score[k] = e;
            sum += e;
        }
        const float inv = 1.0f / sum;

        // ---- Weighted sum from registers ----
        float ox = 0.f, oy = 0.f, oz = 0.f, ow = 0.f;
        #pragma unroll
        for (int k = 0; k < KWIN; ++k) {
            const int i = k / 5, j = k % 5;
            const float wk2 = score[k] * inv * re[i] * ce[j];
            ox = fmaf(wk2, qg[k].x, ox);
            oy = fmaf(wk2, qg[k].y, oy);
            oz = fmaf(wk2, qg[k].z, oz);
            ow = fmaf(wk2, qg[k].w, ow);
        }
        *reinterpret_cast<float4*>(&out[(size_t)pid * DDIM + lane * 4]) =
            make_float4(ox, oy, oz, ow);
    }
}

// ---------------------------------------------------------------------------
extern "C" void kernel_launch(void* const* d_in, const int* in_sizes, int n_in,
                              void* d_out, int out_size, void* d_ws, size_t ws_size,
                              hipStream_t stream) {
    const float* q   = (const float*)d_in[0];
    const float* c_t = (const float*)d_in[1];
    const float* p_t = (const float*)d_in[2];
    const float* W_a = (const float*)d_in[3];
    float* out = (float*)d_out;

    fused_local_attn<<<BN / PIDS_PER_BLK, THREADS, 0, stream>>>(q, c_t, p_t, W_a, out);
}